// Round 1
// baseline (99.447 us; speedup 1.0000x reference)
//
#include <hip/hip_runtime.h>
#include <math.h>

#define N_QUBITS 4
#define N_LAYERS 6
#define NW (N_LAYERS * N_QUBITS)

// One thread = one batch sample. 16 complex amplitudes live in registers.
// Qubit q <-> bit (8 >> q) of the flat state index (ref layout [B,2,2,2,2]).
__global__ __launch_bounds__(256) void qlayer_kernel(
    const float* __restrict__ x,        // [B, 4]
    const float* __restrict__ weights,  // [6, 4]
    float* __restrict__ out,            // [B, 4]
    int B)
{
    __shared__ float wc[NW];
    __shared__ float ws[NW];
    const int tid = threadIdx.x;
    if (tid < NW) {
        float t = weights[tid] * 0.5f;
        wc[tid] = __cosf(t);
        ws[tid] = __sinf(t);
    }
    __syncthreads();

    const int b = blockIdx.x * blockDim.x + tid;
    if (b >= B) return;

    // ---- data-encoding RY(x_q) applied to |0000>: product state, real amps
    const float4 xv = reinterpret_cast<const float4*>(x)[b];
    float cx[4], sx[4];
    {
        float h0 = xv.x * 0.5f, h1 = xv.y * 0.5f, h2 = xv.z * 0.5f, h3 = xv.w * 0.5f;
        cx[0] = __cosf(h0); sx[0] = __sinf(h0);
        cx[1] = __cosf(h1); sx[1] = __sinf(h1);
        cx[2] = __cosf(h2); sx[2] = __sinf(h2);
        cx[3] = __cosf(h3); sx[3] = __sinf(h3);
    }

    float re[16], im[16];
#pragma unroll
    for (int idx = 0; idx < 16; ++idx) {
        float a = ((idx & 8) ? sx[0] : cx[0]) * ((idx & 4) ? sx[1] : cx[1]);
        a *= ((idx & 2) ? sx[2] : cx[2]) * ((idx & 1) ? sx[3] : cx[3]);
        re[idx] = a;
        im[idx] = 0.0f;
    }

    // ---- entangler layers: RX(w) on each wire, then CNOT ring
#pragma unroll
    for (int l = 0; l < N_LAYERS; ++l) {
#pragma unroll
        for (int q = 0; q < N_QUBITS; ++q) {
            const float ct = wc[l * 4 + q];
            const float sn = ws[l * 4 + q];
            const int mask = 8 >> q;
#pragma unroll
            for (int idx = 0; idx < 16; ++idx) {
                if (idx & mask) continue;
                const int j = idx | mask;
                const float r0 = re[idx], u0 = im[idx];
                const float r1 = re[j],   u1 = im[j];
                // U = [[ct, -i s],[-i s, ct]]
                re[idx] = ct * r0 + sn * u1;
                im[idx] = ct * u0 - sn * r1;
                re[j]   = ct * r1 + sn * u0;
                im[j]   = ct * u1 - sn * r0;
            }
        }
        // CNOT(q, (q+1)%4), applied sequentially — register swaps (free)
#pragma unroll
        for (int q = 0; q < N_QUBITS; ++q) {
            const int cmask = 8 >> q;
            const int tmask = 8 >> ((q + 1) & 3);
#pragma unroll
            for (int idx = 0; idx < 16; ++idx) {
                if ((idx & cmask) && !(idx & tmask)) {
                    const int j = idx | tmask;
                    float tr = re[idx]; re[idx] = re[j]; re[j] = tr;
                    float ti = im[idx]; im[idx] = im[j]; im[j] = ti;
                }
            }
        }
    }

    // ---- <Z_q> from probabilities
    float z0 = 0.f, z1 = 0.f, z2 = 0.f, z3 = 0.f;
#pragma unroll
    for (int idx = 0; idx < 16; ++idx) {
        const float p = re[idx] * re[idx] + im[idx] * im[idx];
        z0 += (idx & 8) ? -p : p;
        z1 += (idx & 4) ? -p : p;
        z2 += (idx & 2) ? -p : p;
        z3 += (idx & 1) ? -p : p;
    }
    reinterpret_cast<float4*>(out)[b] = make_float4(z0, z1, z2, z3);
}

extern "C" void kernel_launch(void* const* d_in, const int* in_sizes, int n_in,
                              void* d_out, int out_size, void* d_ws, size_t ws_size,
                              hipStream_t stream) {
    const float* x = (const float*)d_in[0];
    const float* weights = (const float*)d_in[1];
    float* out = (float*)d_out;
    const int B = in_sizes[0] / 4;

    const int block = 256;
    const int grid = (B + block - 1) / block;
    qlayer_kernel<<<grid, block, 0, stream>>>(x, weights, out, B);
}

// Round 2
// 83.043 us; speedup vs baseline: 1.1975x; 1.1975x over previous
//
#include <hip/hip_runtime.h>
#include <math.h>

#define N_QUBITS 4
#define N_LAYERS 6
#define NW (N_LAYERS * N_QUBITS)

// ---------------------------------------------------------------------------
// Prep kernel (1 block): build the fixed entangler unitary W (16x16 complex),
// then S_q = Re(W^dag Z_q W) (real symmetric), then contract to the 4x81
// multilinear coefficient table C:
//   out_q(x) = sum_{t in {I,Z,X}^4} C_q[t] * prod_p (1, cos x_p, sin x_p)[t_p]
// using psi0 psi0^T = prod_p (1/2)(I + cos x_p Z + sin x_p X)  (RY encoding).
// Qubit p <-> state-index bit (8 >> p), matching ref layout [B,2,2,2,2].
// ---------------------------------------------------------------------------
__global__ __launch_bounds__(256) void qprep_kernel(
    const float* __restrict__ weights, float* __restrict__ Ctab)
{
    __shared__ float Wr[16][16]; // [row k][col i]
    __shared__ float Wi[16][16];
    __shared__ float S[4][16][16];
    __shared__ float wc[NW], ws[NW];
    const int tid = threadIdx.x;
    if (tid < NW) {
        float t = weights[tid] * 0.5f;
        wc[tid] = cosf(t);
        ws[tid] = sinf(t);
    }
    __syncthreads();

    // Phase 1: threads 0..15 each build one column of W = circuit applied to e_col
    if (tid < 16) {
        float re[16], im[16];
        for (int k = 0; k < 16; ++k) { re[k] = (k == tid) ? 1.f : 0.f; im[k] = 0.f; }
        for (int l = 0; l < N_LAYERS; ++l) {
            for (int q = 0; q < 4; ++q) {
                const float ct = wc[l * 4 + q], sn = ws[l * 4 + q];
                const int mask = 8 >> q;
                for (int idx = 0; idx < 16; ++idx) {
                    if (idx & mask) continue;
                    const int j = idx | mask;
                    float r0 = re[idx], u0 = im[idx], r1 = re[j], u1 = im[j];
                    re[idx] = ct * r0 + sn * u1; im[idx] = ct * u0 - sn * r1;
                    re[j]   = ct * r1 + sn * u0; im[j]   = ct * u1 - sn * r0;
                }
            }
            for (int q = 0; q < 4; ++q) {
                const int cm = 8 >> q, tm = 8 >> ((q + 1) & 3);
                for (int idx = 0; idx < 16; ++idx) {
                    if ((idx & cm) && !(idx & tm)) {
                        const int j = idx | tm;
                        float t0 = re[idx]; re[idx] = re[j]; re[j] = t0;
                        float t1 = im[idx]; im[idx] = im[j]; im[j] = t1;
                    }
                }
            }
        }
        for (int k = 0; k < 16; ++k) { Wr[k][tid] = re[k]; Wi[k][tid] = im[k]; }
    }
    __syncthreads();

    // Phase 2: thread (i,j) computes S_q[i][j] = sum_k z_q(k) Re(W[k,i] W*[k,j])
    {
        const int i = tid >> 4, j = tid & 15;
        float acc[4] = {0.f, 0.f, 0.f, 0.f};
        for (int k = 0; k < 16; ++k) {
            const float prod = Wr[k][i] * Wr[k][j] + Wi[k][i] * Wi[k][j];
            for (int q = 0; q < 4; ++q)
                acc[q] += (k & (8 >> q)) ? -prod : prod;
        }
        for (int q = 0; q < 4; ++q) S[q][i][j] = acc[q];
    }
    __syncthreads();

    // Phase 3: C_q[t] = (1/16) sum_i (-1)^popc(i&zm) S_q[i][i^xm]
    if (tid < 81) {
        const int t1 = tid / 27, t2 = (tid / 9) % 3, t3 = (tid / 3) % 3, t4 = tid % 3;
        const int tp[4] = {t1, t2, t3, t4};
        int zm = 0, xm = 0;
        for (int p = 0; p < 4; ++p) {
            if (tp[p] == 1)      zm |= (8 >> p);
            else if (tp[p] == 2) xm |= (8 >> p);
        }
        for (int q = 0; q < 4; ++q) {
            float acc = 0.f;
            for (int i = 0; i < 16; ++i) {
                const float v = S[q][i][i ^ xm];
                acc += (__popc(i & zm) & 1) ? -v : v;
            }
            Ctab[q * 81 + tid] = acc * 0.0625f;
        }
    }
}

// ---------------------------------------------------------------------------
// Main kernel: per sample, evaluate 4 multilinear forms (81 coeffs each).
// Coefficient indices are wave-uniform literals -> scalar (s_load) traffic.
// 320 FMA + 8 fast-trig per thread.
// ---------------------------------------------------------------------------
__global__ __launch_bounds__(256) void qeval_kernel(
    const float* __restrict__ x, const float* __restrict__ Ctab,
    float* __restrict__ out, int B)
{
    const int b = blockIdx.x * blockDim.x + threadIdx.x;
    if (b >= B) return;
    const float4 xv = reinterpret_cast<const float4*>(x)[b];

    float v0[3], v1[3], v2[3], v3[3];
    v0[0] = 1.f; v0[1] = __cosf(xv.x); v0[2] = __sinf(xv.x);
    v1[0] = 1.f; v1[1] = __cosf(xv.y); v1[2] = __sinf(xv.y);
    v2[0] = 1.f; v2[1] = __cosf(xv.z); v2[2] = __sinf(xv.z);
    v3[0] = 1.f; v3[1] = __cosf(xv.w); v3[2] = __sinf(xv.w);

    float o[4];
#pragma unroll
    for (int q = 0; q < 4; ++q) {
        const float* __restrict__ Cq = Ctab + q * 81;
        float s1 = 0.f;
#pragma unroll
        for (int t1 = 0; t1 < 3; ++t1) {
            float s2 = 0.f;
#pragma unroll
            for (int t2 = 0; t2 < 3; ++t2) {
                float s3 = 0.f;
#pragma unroll
                for (int t3 = 0; t3 < 3; ++t3) {
                    const int base = ((t1 * 3 + t2) * 3 + t3) * 3;
                    float e = Cq[base];
                    e = fmaf(Cq[base + 1], v3[1], e);
                    e = fmaf(Cq[base + 2], v3[2], e);
                    s3 = (t3 == 0) ? (s3 + e) : fmaf(e, v2[t3], s3);
                }
                s2 = (t2 == 0) ? (s2 + s3) : fmaf(s3, v1[t2], s2);
            }
            s1 = (t1 == 0) ? (s1 + s2) : fmaf(s2, v0[t1], s1);
        }
        o[q] = s1;
    }
    reinterpret_cast<float4*>(out)[b] = make_float4(o[0], o[1], o[2], o[3]);
}

extern "C" void kernel_launch(void* const* d_in, const int* in_sizes, int n_in,
                              void* d_out, int out_size, void* d_ws, size_t ws_size,
                              hipStream_t stream) {
    const float* x = (const float*)d_in[0];
    const float* weights = (const float*)d_in[1];
    float* out = (float*)d_out;
    float* Ctab = (float*)d_ws;   // 324 floats
    const int B = in_sizes[0] / 4;

    qprep_kernel<<<1, 256, 0, stream>>>(weights, Ctab);

    const int block = 256;
    const int grid = (B + block - 1) / block;
    qeval_kernel<<<grid, block, 0, stream>>>(x, Ctab, out, B);
}